// Round 6
// baseline (192.613 us; speedup 1.0000x reference)
//
#include <hip/hip_runtime.h>

typedef __bf16 bf16x8 __attribute__((ext_vector_type(8)));
typedef float f32x4 __attribute__((ext_vector_type(4)));
typedef unsigned int u32x4 __attribute__((ext_vector_type(4)));

__device__ __forceinline__ unsigned short f2bf(float f) {
  unsigned int u = __float_as_uint(f);
  u += 0x7FFFu + ((u >> 16) & 1u);   // round-to-nearest-even
  return (unsigned short)(u >> 16);
}

__device__ __forceinline__ bf16x8 load_frag(const unsigned short* p) {
  u32x4 v = *(const u32x4*)p;
  return __builtin_bit_cast(bf16x8, v);
}

// ---------------------------------------------------------------------------
// Convert all four used fp32 tensors to bf16 (object dims zero-padded to a
// multiple of 16 for MFMA M-tiling). Verified R1/R3 (absmax 0.0).
// Also zeroes the completion counter (ws is 0xAA-poisoned before each call).
// ---------------------------------------------------------------------------
__global__ __launch_bounds__(256) void convert_all(
    const float* __restrict__ im, const float* __restrict__ s,
    const float* __restrict__ pred, const float* __restrict__ crp,
    unsigned short* __restrict__ imb, unsigned short* __restrict__ sb,
    unsigned short* __restrict__ pb, unsigned short* __restrict__ cb,
    unsigned int* __restrict__ counter)
{
  int b = blockIdx.x;
  if (b == 0 && threadIdx.x == 0) *counter = 0u;
  const float* src; unsigned short* dst; int O, OP, base;
  if (b < 768)       { src = im;   dst = imb; O = 36; OP = 48; base = 0; }
  else if (b < 1568) { src = s;    dst = sb;  O = 50; OP = 50; base = 768; }
  else if (b < 2080) { src = pred; dst = pb;  O = 25; OP = 32; base = 1568; }
  else               { src = crp;  dst = cb;  O = 30; OP = 30; base = 2080; }
  int tid = (b - base) * 256 + (int)threadIdx.x;          // one thread = 4 floats
  int total = 128 * OP * 32;
  if (tid >= total) return;
  int d4 = tid & 31;
  int o  = (tid >> 5) % OP;
  int bb = tid / (OP * 32);
  unsigned short r0 = 0, r1 = 0, r2 = 0, r3 = 0;
  if (o < O) {
    const float4 v = *(const float4*)(src + ((bb * O + o) << 7) + (d4 << 2));
    r0 = f2bf(v.x); r1 = f2bf(v.y); r2 = f2bf(v.z); r3 = f2bf(v.w);
  }
  ushort4 outv; outv.x = r0; outv.y = r1; outv.z = r2; outv.w = r3;
  *(ushort4*)(dst + (size_t)tid * 4) = outv;
}

// ---------------------------------------------------------------------------
// t2i pooled score, ONE image per block vs one 16-caption group — the R1
// register shape (af[MT][4] = 48 VGPR, no spill; R1 measured fast).
// D mapping (verified R1/R3/R5): col = lane&15 (B row), row = (lane>>4)*4+reg.
// ---------------------------------------------------------------------------
template<int MT, int W>
__device__ __forceinline__ void t2i_one(
    const unsigned short* __restrict__ A,    // [128, MT*16, 128] bf16
    const unsigned short* __restrict__ Bw,   // [128, W, 128] bf16
    const int* __restrict__ obj_l, const int* __restrict__ cap_l,
    float* __restrict__ pooled,              // [128,128] fp32
    int vb, float* wmax)                     // wmax: LDS >= 16*W floats
{
  const int i   = vb >> 3;
  const int cg0 = (vb & 7) * 16;
  const int tid = threadIdx.x;
  const int wv = tid >> 6, lane = tid & 63;
  const int quad = lane >> 4, n16 = lane & 15;
  const int obj_li = obj_l[i];

  bf16x8 af[MT][4];
  const unsigned short* Abase = A + (((size_t)i * (MT * 16) + n16) << 7) + quad * 8;
#pragma unroll
  for (int t = 0; t < MT; ++t)
#pragma unroll
    for (int s = 0; s < 4; ++s)
      af[t][s] = load_frag(Abase + ((t * 16) << 7) + s * 32);

  const unsigned short* Bbase = Bw + (((size_t)cg0 * W + n16) << 7) + quad * 8;

  for (int nt = wv; nt < W; nt += 4) {       // 16*W/16 = W tiles, exact
    const unsigned short* bp = Bbase + ((nt * 16) << 7);
    bf16x8 bfrag[4];
#pragma unroll
    for (int s = 0; s < 4; ++s) bfrag[s] = load_frag(bp + s * 32);

    f32x4 acc[MT];
#pragma unroll
    for (int t = 0; t < MT; ++t) { f32x4 z = {0.f, 0.f, 0.f, 0.f}; acc[t] = z; }
#pragma unroll
    for (int s = 0; s < 4; ++s)
#pragma unroll
      for (int t = 0; t < MT; ++t)
        acc[t] = __builtin_amdgcn_mfma_f32_16x16x32_bf16(af[t][s], bfrag[s], acc[t], 0, 0, 0);

    float m = -3.0e38f;
#pragma unroll
    for (int t = 0; t < MT; ++t)
#pragma unroll
      for (int r = 0; r < 4; ++r) {
        int o = t * 16 + quad * 4 + r;
        if (o < obj_li) m = fmaxf(m, acc[t][r]);
      }
    m = fmaxf(m, __shfl_xor(m, 16));
    m = fmaxf(m, __shfl_xor(m, 32));
    if (quad == 0) wmax[nt * 16 + n16] = m;
  }
  __syncthreads();

  if (tid < 16) {
    float ssum = 0.f;
    const float* wp = wmax + tid * W;
    for (int w = 0; w < W; ++w) ssum += wp[w];
    const int c = cg0 + tid;
    pooled[(i << 7) + c] = ssum / (float)cap_l[c];
  }
}

// ---------------------------------------------------------------------------
// Inline hinge loss, 256 threads, run by the LAST block (R4/R5-verified).
// ---------------------------------------------------------------------------
__device__ __forceinline__ void loss_inline(
    const float* __restrict__ p1, const float* __restrict__ p2,
    float* __restrict__ out, float* smem)
{
  float* diag    = smem;                // [128]
  int*   rowmaxi = (int*)(smem + 128);  // [128]
  float* colmax  = smem + 256;          // [2][128]
  float* wred    = smem + 512;          // [4]
  const int tid = threadIdx.x;
  const int j = tid & 127, half = tid >> 7;
  if (half == 0) {
    diag[j] = p1[j * 129] + p2[j * 129];
    rowmaxi[j] = 0;                     // float bits of 0.0f
  }
  __syncthreads();

  float colp = 0.f;
  for (int rr = 0; rr < 64; ++rr) {
    const int row = half * 64 + rr;
    const float sc = p1[row * 128 + j] + p2[row * 128 + j];
    float rh = (j == row) ? 0.f : fmaxf(0.2f + sc - diag[row], 0.f);
    const float ch = (j == row) ? 0.f : fmaxf(0.2f + sc - diag[j], 0.f);
    colp = fmaxf(colp, ch);
#pragma unroll
    for (int o = 32; o; o >>= 1) rh = fmaxf(rh, __shfl_xor(rh, o));
    if ((tid & 63) == 0) atomicMax(&rowmaxi[row], __float_as_int(rh));
  }
  colmax[half * 128 + j] = colp;
  __syncthreads();

  float v;
  if (tid < 128) v = __int_as_float(rowmaxi[tid]);
  else           v = fmaxf(colmax[tid - 128], colmax[128 + (tid - 128)]);
#pragma unroll
  for (int o = 32; o; o >>= 1) v += __shfl_xor(v, o);
  if ((tid & 63) == 0) wred[tid >> 6] = v;
  __syncthreads();
  if (tid == 0) out[0] = wred[0] + wred[1] + wred[2] + wred[3];
}

// ---------------------------------------------------------------------------
// Fused t2i (both terms, IM=1) + last-block loss. Plain launch_bounds(256):
// R1's proven allocator setting. Grid 2048: [0,1024) term1, [1024,2048) term2.
// ---------------------------------------------------------------------------
__global__ __launch_bounds__(256) void t2i_loss(
    const unsigned short* __restrict__ imb, const unsigned short* __restrict__ sb,
    const unsigned short* __restrict__ pb,  const unsigned short* __restrict__ cb,
    const int* __restrict__ im_l, const int* __restrict__ s_l,
    const int* __restrict__ pred_l, const int* __restrict__ crl,
    float* __restrict__ p1, float* __restrict__ p2,
    unsigned int* __restrict__ counter, float* __restrict__ out)
{
  __shared__ float smem[16 * 50];
  __shared__ int lastFlag;
  const int b = blockIdx.x;

  if (b < 1024) t2i_one<3, 50>(imb, sb, im_l, s_l, p1, b, smem);
  else          t2i_one<2, 30>(pb, cb, pred_l, crl, p2, b - 1024, smem);

  __syncthreads();                  // drain pooled stores before signaling
  if (threadIdx.x == 0) {
    __threadfence();                // agent-scope release
    lastFlag = (atomicAdd(counter, 1u) == 2047u) ? 1 : 0;
  }
  __syncthreads();
  if (lastFlag) {
    __threadfence();                // acquire
    loss_inline(p1, p2, out, smem);
  }
}

// ---------------------------------------------------------------------------
extern "C" void kernel_launch(void* const* d_in, const int* in_sizes, int n_in,
                              void* d_out, int out_size, void* d_ws, size_t ws_size,
                              hipStream_t stream)
{
  const float* im     = (const float*)d_in[0];
  const int*   im_l   = (const int*)  d_in[1];
  const float* s32    = (const float*)d_in[2];
  const int*   s_l    = (const int*)  d_in[3];
  const float* pred   = (const float*)d_in[4];
  const int*   pred_l = (const int*)  d_in[5];
  // d_in[6], d_in[7] unused by the reference.
  const float* crp    = (const float*)d_in[8];
  const int*   crl    = (const int*)  d_in[9];

  char* ws = (char*)d_ws;
  const size_t off_imb = 0;
  const size_t off_sb  = off_imb + (size_t)128 * 48 * 128 * 2;
  const size_t off_pb  = off_sb  + (size_t)128 * 50 * 128 * 2;
  const size_t off_cb  = off_pb  + (size_t)128 * 32 * 128 * 2;
  const size_t off_p1  = off_cb  + (size_t)128 * 30 * 128 * 2;
  const size_t off_p2  = off_p1  + (size_t)128 * 128 * 4;
  const size_t off_ctr = off_p2  + (size_t)128 * 128 * 4;

  unsigned short* imb = (unsigned short*)(ws + off_imb);
  unsigned short* sb  = (unsigned short*)(ws + off_sb);
  unsigned short* pb  = (unsigned short*)(ws + off_pb);
  unsigned short* cb  = (unsigned short*)(ws + off_cb);
  float* p1 = (float*)(ws + off_p1);
  float* p2 = (float*)(ws + off_p2);
  unsigned int* counter = (unsigned int*)(ws + off_ctr);

  hipLaunchKernelGGL(convert_all, dim3(2560), dim3(256), 0, stream,
                     im, s32, pred, crp, imb, sb, pb, cb, counter);
  hipLaunchKernelGGL(t2i_loss, dim3(2048), dim3(256), 0, stream,
                     imb, sb, pb, cb, im_l, s_l, pred_l, crl,
                     p1, p2, counter, (float*)d_out);
}

// Round 7
// 192.103 us; speedup vs baseline: 1.0027x; 1.0027x over previous
//
#include <hip/hip_runtime.h>

typedef __bf16 bf16x8 __attribute__((ext_vector_type(8)));
typedef float f32x4 __attribute__((ext_vector_type(4)));
typedef unsigned int u32x4 __attribute__((ext_vector_type(4)));

#define ASTRIDE 132   // LDS A-tile row stride in bf16 elems (264 B): 2-way max bank aliasing (free)

__device__ __forceinline__ unsigned short f2bf(float f) {
  unsigned int u = __float_as_uint(f);
  u += 0x7FFFu + ((u >> 16) & 1u);   // round-to-nearest-even
  return (unsigned short)(u >> 16);
}

__device__ __forceinline__ bf16x8 load_frag(const unsigned short* p) {
  u32x4 v = *(const u32x4*)p;
  return __builtin_bit_cast(bf16x8, v);
}

// ---------------------------------------------------------------------------
// Convert the two B-side fp32 tensors (s, c_r_pred) to bf16, flat copy
// (exact grid: 800 + 480 blocks x 1024 floats). Also zeroes the counter.
// A-side tensors are converted in-block by t2i_loss while staging to LDS.
// ---------------------------------------------------------------------------
__global__ __launch_bounds__(256) void convert_b(
    const float* __restrict__ s, const float* __restrict__ crp,
    unsigned short* __restrict__ sb, unsigned short* __restrict__ cb,
    unsigned int* __restrict__ counter)
{
  const int b = blockIdx.x;
  if (b == 0 && threadIdx.x == 0) *counter = 0u;   // ws is 0xAA-poisoned
  const float4* src; ushort4* dst; int idx;
  if (b < 800) { src = (const float4*)s;   dst = (ushort4*)sb; idx = b * 256 + (int)threadIdx.x; }
  else         { src = (const float4*)crp; dst = (ushort4*)cb; idx = (b - 800) * 256 + (int)threadIdx.x; }
  float4 v = src[idx];
  ushort4 o; o.x = f2bf(v.x); o.y = f2bf(v.y); o.z = f2bf(v.z); o.w = f2bf(v.w);
  dst[idx] = o;
}

// ---------------------------------------------------------------------------
// t2i pooled score, canonical-LDS form: block stages its image's A rows
// (fp32 -> bf16) into LDS once, then per N-tile reads A fragments via
// ds_read_b128 (no large register array -> no remat/spill, the R4-R6 bug).
// D mapping (verified R1/R3/R5/R6): col = lane&15 (B row), row = quad*4+reg.
// ---------------------------------------------------------------------------
template<int MT, int W, int O>
__device__ __forceinline__ void t2i_lds(
    const float* __restrict__ A32,         // [128][O][128] fp32 (original input)
    const unsigned short* __restrict__ Bw, // [128][W][128] bf16 (staged)
    const int* __restrict__ obj_l, const int* __restrict__ cap_l,
    float* __restrict__ pooled,            // [128][128] fp32
    int vb, unsigned short* aT, float* wmax)
{
  const int i   = vb >> 3;
  const int cg0 = (vb & 7) * 16;
  const int tid = threadIdx.x;
  const int wv = tid >> 6, lane = tid & 63;
  const int quad = lane >> 4, n16 = lane & 15;
  const int obj_li = obj_l[i];

  // Stage A: O rows x 128 cols, fp32 -> bf16, into aT[row*ASTRIDE + col].
  const float4* src = (const float4*)(A32 + (size_t)i * O * 128);
  for (int c = tid; c < O * 32; c += 256) {
    const int row = c >> 5, col4 = c & 31;
    float4 v = src[c];
    ushort4 o; o.x = f2bf(v.x); o.y = f2bf(v.y); o.z = f2bf(v.z); o.w = f2bf(v.w);
    *(ushort4*)(aT + row * ASTRIDE + col4 * 4) = o;
  }
  __syncthreads();
  // Rows O..MT*16-1 are uninitialized LDS: harmless, masked out at max time.

  const unsigned short* Bbase = Bw + ((size_t)cg0 * W + n16) * 128 + quad * 8;
  const unsigned short* aTl   = aT + n16 * ASTRIDE + quad * 8;

  for (int nt = wv; nt < W; nt += 4) {       // 16*W rows / 16 = W tiles, exact
    const unsigned short* bp = Bbase + (size_t)(nt * 16) * 128;
    bf16x8 bfrag[4];
#pragma unroll
    for (int s = 0; s < 4; ++s) bfrag[s] = load_frag(bp + s * 32);

    f32x4 acc[MT];
#pragma unroll
    for (int t = 0; t < MT; ++t) { f32x4 z = {0.f, 0.f, 0.f, 0.f}; acc[t] = z; }
#pragma unroll
    for (int s = 0; s < 4; ++s)
#pragma unroll
      for (int t = 0; t < MT; ++t) {
        // ds_read_b128 from the staged A tile (fresh each iter, no live array)
        u32x4 av = *(const u32x4*)(aTl + t * 16 * ASTRIDE + s * 32);
        acc[t] = __builtin_amdgcn_mfma_f32_16x16x32_bf16(
            __builtin_bit_cast(bf16x8, av), bfrag[s], acc[t], 0, 0, 0);
      }

    float m = -3.0e38f;
#pragma unroll
    for (int t = 0; t < MT; ++t)
#pragma unroll
      for (int r = 0; r < 4; ++r) {
        int o = t * 16 + quad * 4 + r;
        if (o < obj_li) m = fmaxf(m, acc[t][r]);
      }
    m = fmaxf(m, __shfl_xor(m, 16));
    m = fmaxf(m, __shfl_xor(m, 32));
    if (quad == 0) wmax[nt * 16 + n16] = m;
  }
  __syncthreads();

  if (tid < 16) {
    float ssum = 0.f;
    const float* wp = wmax + tid * W;
    for (int w = 0; w < W; ++w) ssum += wp[w];
    const int c = cg0 + tid;
    pooled[(i << 7) + c] = ssum / (float)cap_l[c];
  }
}

// ---------------------------------------------------------------------------
// Inline hinge loss, 256 threads, run by the LAST block (R4/R5/R6-verified).
// ---------------------------------------------------------------------------
__device__ __forceinline__ void loss_inline(
    const float* __restrict__ p1, const float* __restrict__ p2,
    float* __restrict__ out, float* smem)
{
  float* diag    = smem;                // [128]
  int*   rowmaxi = (int*)(smem + 128);  // [128]
  float* colmax  = smem + 256;          // [2][128]
  float* wred    = smem + 512;          // [4]
  const int tid = threadIdx.x;
  const int j = tid & 127, half = tid >> 7;
  if (half == 0) {
    diag[j] = p1[j * 129] + p2[j * 129];
    rowmaxi[j] = 0;                     // float bits of 0.0f
  }
  __syncthreads();

  float colp = 0.f;
  for (int rr = 0; rr < 64; ++rr) {
    const int row = half * 64 + rr;
    const float sc = p1[row * 128 + j] + p2[row * 128 + j];
    float rh = (j == row) ? 0.f : fmaxf(0.2f + sc - diag[row], 0.f);
    const float ch = (j == row) ? 0.f : fmaxf(0.2f + sc - diag[j], 0.f);
    colp = fmaxf(colp, ch);
#pragma unroll
    for (int o = 32; o; o >>= 1) rh = fmaxf(rh, __shfl_xor(rh, o));
    if ((tid & 63) == 0) atomicMax(&rowmaxi[row], __float_as_int(rh));
  }
  colmax[half * 128 + j] = colp;
  __syncthreads();

  float v;
  if (tid < 128) v = __int_as_float(rowmaxi[tid]);
  else           v = fmaxf(colmax[tid - 128], colmax[128 + (tid - 128)]);
#pragma unroll
  for (int o = 32; o; o >>= 1) v += __shfl_xor(v, o);
  if ((tid & 63) == 0) wred[tid >> 6] = v;
  __syncthreads();
  if (tid == 0) out[0] = wred[0] + wred[1] + wred[2] + wred[3];
}

// ---------------------------------------------------------------------------
// Fused t2i (both terms) + last-block loss. Grid 2048:
// [0,1024) term1 (im vs s), [1024,2048) term2 (pred vs c_r_pred).
// ---------------------------------------------------------------------------
__global__ __launch_bounds__(256) void t2i_loss(
    const float* __restrict__ im, const float* __restrict__ pred,
    const unsigned short* __restrict__ sb, const unsigned short* __restrict__ cb,
    const int* __restrict__ im_l, const int* __restrict__ s_l,
    const int* __restrict__ pred_l, const int* __restrict__ crl,
    float* __restrict__ p1, float* __restrict__ p2,
    unsigned int* __restrict__ counter, float* __restrict__ out)
{
  __shared__ unsigned short aT[48 * ASTRIDE];   // 12.7 KB
  __shared__ float wmax[16 * 50];               // 3.2 KB
  __shared__ int lastFlag;
  const int b = blockIdx.x;

  if (b < 1024) t2i_lds<3, 50, 36>(im,   sb, im_l,   s_l, p1, b,        aT, wmax);
  else          t2i_lds<2, 30, 25>(pred, cb, pred_l, crl, p2, b - 1024, aT, wmax);

  __syncthreads();                  // drain pooled stores before signaling
  if (threadIdx.x == 0) {
    __threadfence();                // agent-scope release
    lastFlag = (atomicAdd(counter, 1u) == 2047u) ? 1 : 0;
  }
  __syncthreads();
  if (lastFlag) {
    __threadfence();                // acquire
    loss_inline(p1, p2, out, (float*)aT);   // reuse LDS (16B-aligned, 516 floats)
  }
}

// ---------------------------------------------------------------------------
extern "C" void kernel_launch(void* const* d_in, const int* in_sizes, int n_in,
                              void* d_out, int out_size, void* d_ws, size_t ws_size,
                              hipStream_t stream)
{
  const float* im     = (const float*)d_in[0];
  const int*   im_l   = (const int*)  d_in[1];
  const float* s32    = (const float*)d_in[2];
  const int*   s_l    = (const int*)  d_in[3];
  const float* pred   = (const float*)d_in[4];
  const int*   pred_l = (const int*)  d_in[5];
  // d_in[6], d_in[7] unused by the reference.
  const float* crp    = (const float*)d_in[8];
  const int*   crl    = (const int*)  d_in[9];

  char* ws = (char*)d_ws;
  const size_t off_sb  = 0;
  const size_t off_cb  = off_sb + (size_t)128 * 50 * 128 * 2;   // 1,638,400
  const size_t off_p1  = off_cb + (size_t)128 * 30 * 128 * 2;   // +983,040
  const size_t off_p2  = off_p1 + (size_t)128 * 128 * 4;
  const size_t off_ctr = off_p2 + (size_t)128 * 128 * 4;

  unsigned short* sb = (unsigned short*)(ws + off_sb);
  unsigned short* cb = (unsigned short*)(ws + off_cb);
  float* p1 = (float*)(ws + off_p1);
  float* p2 = (float*)(ws + off_p2);
  unsigned int* counter = (unsigned int*)(ws + off_ctr);

  hipLaunchKernelGGL(convert_b, dim3(1280), dim3(256), 0, stream,
                     s32, crp, sb, cb, counter);
  hipLaunchKernelGGL(t2i_loss, dim3(2048), dim3(256), 0, stream,
                     im, pred, sb, cb, im_l, s_l, pred_l, crl,
                     p1, p2, counter, (float*)d_out);
}

// Round 8
// 133.184 us; speedup vs baseline: 1.4462x; 1.4424x over previous
//
#include <hip/hip_runtime.h>

typedef __bf16 bf16x8 __attribute__((ext_vector_type(8)));
typedef float f32x4 __attribute__((ext_vector_type(4)));
typedef unsigned int u32x4 __attribute__((ext_vector_type(4)));

#define ASTRIDE 132   // LDS A-tile row stride in bf16 (264 B): max 2-way bank aliasing (free, m136)

__device__ __forceinline__ unsigned short f2bf(float f) {
  unsigned int u = __float_as_uint(f);
  u += 0x7FFFu + ((u >> 16) & 1u);   // round-to-nearest-even
  return (unsigned short)(u >> 16);
}

__device__ __forceinline__ bf16x8 load_frag(const unsigned short* p) {
  u32x4 v = *(const u32x4*)p;
  return __builtin_bit_cast(bf16x8, v);
}

// ---------------------------------------------------------------------------
// Convert the two B-side fp32 tensors (s, c_r_pred) to bf16 (R7-verified).
// A-side tensors are converted in-block by the t2i kernel while staging LDS.
// ---------------------------------------------------------------------------
__global__ __launch_bounds__(256) void convert_b(
    const float* __restrict__ s, const float* __restrict__ crp,
    unsigned short* __restrict__ sb, unsigned short* __restrict__ cb)
{
  const int b = blockIdx.x;
  const float4* src; ushort4* dst; int idx;
  if (b < 800) { src = (const float4*)s;   dst = (ushort4*)sb; idx = b * 256 + (int)threadIdx.x; }
  else         { src = (const float4*)crp; dst = (ushort4*)cb; idx = (b - 800) * 256 + (int)threadIdx.x; }
  float4 v = src[idx];
  ushort4 o; o.x = f2bf(v.x); o.y = f2bf(v.y); o.z = f2bf(v.z); o.w = f2bf(v.w);
  dst[idx] = o;
}

// ---------------------------------------------------------------------------
// t2i pooled score, canonical-LDS form (R7-verified, VGPR=40, no remat):
// block stages its image's A rows (fp32 -> bf16) into LDS once, then per
// N-tile reads A fragments via ds_read_b128. NO completion machinery — the
// R5-R7 post-mortems show the device-scope fence/atomic path cost ~80-100 us
// (cross-XCD release = L2 writeback per block); a separate launch is cheaper.
// D mapping (verified R1..R7): col = lane&15 (B row), row = quad*4 + reg.
// ---------------------------------------------------------------------------
template<int MT, int W, int O>
__device__ __forceinline__ void t2i_lds(
    const float* __restrict__ A32,         // [128][O][128] fp32 (original input)
    const unsigned short* __restrict__ Bw, // [128][W][128] bf16 (staged)
    const int* __restrict__ obj_l, const int* __restrict__ cap_l,
    float* __restrict__ pooled,            // [128][128] fp32
    int vb, unsigned short* aT, float* wmax)
{
  const int i   = vb >> 3;
  const int cg0 = (vb & 7) * 16;
  const int tid = threadIdx.x;
  const int wv = tid >> 6, lane = tid & 63;
  const int quad = lane >> 4, n16 = lane & 15;
  const int obj_li = obj_l[i];

  // Stage A: O rows x 128 cols, fp32 -> bf16, into aT[row*ASTRIDE + col].
  const float4* src = (const float4*)(A32 + (size_t)i * O * 128);
  for (int c = tid; c < O * 32; c += 256) {
    const int row = c >> 5, col4 = c & 31;
    float4 v = src[c];
    ushort4 o; o.x = f2bf(v.x); o.y = f2bf(v.y); o.z = f2bf(v.z); o.w = f2bf(v.w);
    *(ushort4*)(aT + row * ASTRIDE + col4 * 4) = o;
  }
  __syncthreads();
  // Rows O..MT*16-1 are uninitialized LDS: harmless, masked out at max time.

  const unsigned short* Bbase = Bw + ((size_t)cg0 * W + n16) * 128 + quad * 8;
  const unsigned short* aTl   = aT + n16 * ASTRIDE + quad * 8;

  for (int nt = wv; nt < W; nt += 4) {       // 16*W rows / 16 = W tiles, exact
    const unsigned short* bp = Bbase + (size_t)(nt * 16) * 128;
    bf16x8 bfrag[4];
#pragma unroll
    for (int s = 0; s < 4; ++s) bfrag[s] = load_frag(bp + s * 32);

    f32x4 acc[MT];
#pragma unroll
    for (int t = 0; t < MT; ++t) { f32x4 z = {0.f, 0.f, 0.f, 0.f}; acc[t] = z; }
#pragma unroll
    for (int s = 0; s < 4; ++s)
#pragma unroll
      for (int t = 0; t < MT; ++t) {
        u32x4 av = *(const u32x4*)(aTl + t * 16 * ASTRIDE + s * 32);
        acc[t] = __builtin_amdgcn_mfma_f32_16x16x32_bf16(
            __builtin_bit_cast(bf16x8, av), bfrag[s], acc[t], 0, 0, 0);
      }

    float m = -3.0e38f;
#pragma unroll
    for (int t = 0; t < MT; ++t)
#pragma unroll
      for (int r = 0; r < 4; ++r) {
        int o = t * 16 + quad * 4 + r;
        if (o < obj_li) m = fmaxf(m, acc[t][r]);
      }
    m = fmaxf(m, __shfl_xor(m, 16));
    m = fmaxf(m, __shfl_xor(m, 32));
    if (quad == 0) wmax[nt * 16 + n16] = m;
  }
  __syncthreads();

  if (tid < 16) {
    float ssum = 0.f;
    const float* wp = wmax + tid * W;
    for (int w = 0; w < W; ++w) ssum += wp[w];
    const int c = cg0 + tid;
    pooled[(i << 7) + c] = ssum / (float)cap_l[c];
  }
}

__global__ __launch_bounds__(256) void t2i_kernel(
    const float* __restrict__ im, const float* __restrict__ pred,
    const unsigned short* __restrict__ sb, const unsigned short* __restrict__ cb,
    const int* __restrict__ im_l, const int* __restrict__ s_l,
    const int* __restrict__ pred_l, const int* __restrict__ crl,
    float* __restrict__ p1, float* __restrict__ p2)
{
  __shared__ unsigned short aT[48 * ASTRIDE];   // 12.4 KB
  __shared__ float wmax[16 * 50];               // 3.2 KB
  const int b = blockIdx.x;
  if (b < 1024) t2i_lds<3, 50, 36>(im,   sb, im_l,   s_l, p1, b,        aT, wmax);
  else          t2i_lds<2, 30, 25>(pred, cb, pred_l, crl, p2, b - 1024, aT, wmax);
}

// ---------------------------------------------------------------------------
// Hinge loss, one block of 1024 threads, fully coalesced (R3-verified).
// Thread (sub,j) scans 16 rows with j contiguous; row-hinge (diag[row]) and
// col-hinge (diag[j]) from one load pair. Row max: wave shfl + LDS atomicMax
// on float bits (hinges >= 0). Col max: register + LDS tree.
// ---------------------------------------------------------------------------
__global__ __launch_bounds__(1024) void loss_kernel(
    const float* __restrict__ p1, const float* __restrict__ p2,
    float* __restrict__ out)
{
  __shared__ float diag[128];
  __shared__ int   rowmaxi[128];
  __shared__ float colmax[8][128];
  __shared__ float wred[16];
  const int tid = threadIdx.x;
  const int sub = tid >> 7, j = tid & 127;
  if (sub == 0) {
    diag[j] = p1[j * 129] + p2[j * 129];
    rowmaxi[j] = 0;                         // float bits of 0.0f
  }
  __syncthreads();

  float colp = 0.f;
#pragma unroll
  for (int rr = 0; rr < 16; ++rr) {
    const int row = sub * 16 + rr;
    const float sc = p1[row * 128 + j] + p2[row * 128 + j];
    const float dr = diag[row];
    float rh = (j == row) ? 0.f : fmaxf(0.2f + sc - dr, 0.f);
    const float ch = (j == row) ? 0.f : fmaxf(0.2f + sc - diag[j], 0.f);
    colp = fmaxf(colp, ch);
#pragma unroll
    for (int o = 32; o; o >>= 1) rh = fmaxf(rh, __shfl_xor(rh, o));
    if ((tid & 63) == 0) atomicMax(&rowmaxi[row], __float_as_int(rh));
  }
  colmax[sub][j] = colp;
  __syncthreads();
  if (sub < 4) colmax[sub][j] = fmaxf(colmax[sub][j], colmax[sub + 4][j]);
  __syncthreads();
  if (sub < 2) colmax[sub][j] = fmaxf(colmax[sub][j], colmax[sub + 2][j]);
  __syncthreads();
  if (sub < 1) colmax[0][j] = fmaxf(colmax[0][j], colmax[1][j]);
  __syncthreads();

  float v = 0.f;
  if (tid < 128)      v = __int_as_float(rowmaxi[tid]);
  else if (tid < 256) v = colmax[0][tid - 128];
#pragma unroll
  for (int o = 32; o; o >>= 1) v += __shfl_xor(v, o);
  if ((tid & 63) == 0) wred[tid >> 6] = v;
  __syncthreads();
  if (tid == 0) {
    float sfin = 0.f;
    for (int k = 0; k < 16; ++k) sfin += wred[k];
    out[0] = sfin;
  }
}

// ---------------------------------------------------------------------------
extern "C" void kernel_launch(void* const* d_in, const int* in_sizes, int n_in,
                              void* d_out, int out_size, void* d_ws, size_t ws_size,
                              hipStream_t stream)
{
  const float* im     = (const float*)d_in[0];
  const int*   im_l   = (const int*)  d_in[1];
  const float* s32    = (const float*)d_in[2];
  const int*   s_l    = (const int*)  d_in[3];
  const float* pred   = (const float*)d_in[4];
  const int*   pred_l = (const int*)  d_in[5];
  // d_in[6], d_in[7] unused by the reference.
  const float* crp    = (const float*)d_in[8];
  const int*   crl    = (const int*)  d_in[9];

  char* ws = (char*)d_ws;
  const size_t off_sb  = 0;
  const size_t off_cb  = off_sb + (size_t)128 * 50 * 128 * 2;
  const size_t off_p1  = off_cb + (size_t)128 * 30 * 128 * 2;
  const size_t off_p2  = off_p1 + (size_t)128 * 128 * 4;

  unsigned short* sb = (unsigned short*)(ws + off_sb);
  unsigned short* cb = (unsigned short*)(ws + off_cb);
  float* p1 = (float*)(ws + off_p1);
  float* p2 = (float*)(ws + off_p2);

  hipLaunchKernelGGL(convert_b, dim3(1280), dim3(256), 0, stream,
                     s32, crp, sb, cb);
  hipLaunchKernelGGL(t2i_kernel, dim3(2048), dim3(256), 0, stream,
                     im, pred, sb, cb, im_l, s_l, pred_l, crl, p1, p2);
  hipLaunchKernelGGL(loss_kernel, dim3(1), dim3(1024), 0, stream,
                     p1, p2, (float*)d_out);
}